// Round 8
// baseline (220.832 us; speedup 1.0000x reference)
//
#include <hip/hip_runtime.h>
#include <hip/hip_bf16.h>

typedef __attribute__((ext_vector_type(8))) short bh8;   // 8 x bf16 (4 VGPR) MFMA A/B frag
typedef __attribute__((ext_vector_type(4))) float f4;    // 4 x f32 MFMA C/D frag

#define MFMA_BF16 __builtin_amdgcn_mfma_f32_16x16x32_bf16

__device__ __forceinline__ float fast_tanh(float x) {
  float cl = fminf(fmaxf(x, -15.f), 15.f);
  float e = __builtin_amdgcn_exp2f(cl * 2.885390081777927f);  // exp(2x)
  return (e - 1.f) * __builtin_amdgcn_rcpf(e + 1.f);
}

// scalar cast -> compiler emits v_cvt_pk_bf16_f32 for pairs (m240)
__device__ __forceinline__ short bf16hi(float f, float* hf) {
  __hip_bfloat16 h = __float2bfloat16(f);
  *hf = __bfloat162float(h);
  short s;
  __builtin_memcpy(&s, &h, 2);
  return s;
}
__device__ __forceinline__ short bf16s(float f) {
  __hip_bfloat16 h = __float2bfloat16(f);
  short s;
  __builtin_memcpy(&s, &h, 2);
  return s;
}

__device__ __forceinline__ unsigned pack2_bf16(float a, float b) {
  unsigned ua = __float_as_uint(a);
  unsigned ub = __float_as_uint(b);
  ua = (ua + 0x7fffu + ((ua >> 16) & 1u)) >> 16;
  ub = (ub + 0x7fffu + ((ub >> 16) & 1u)) & 0xffff0000u;
  return ua | ub;
}

// ---------------------------------------------------------------------------
// Fully fused: one molecule per 256-thread block (4 waves).
//  phase A: dh[(i,j) pair][h32] = D@df_w+df_b via MFMA -> LDS (57.6 KB,
//           linear [pair][h] bf16; phA uint2 stores and phB uint4 reads are
//           the same dword map; phB read pattern is conflict-free).
//  3x: X1 = (Ch+Cl)@(cfwH+cfwL)+cfb (waves 0-1, 6 MFMAs each);
//      per i (split 4 ways over waves): W' = diag(X1[i])*fc_w hi/lo split,
//      g = dh[i]@(W'h+W'l) (8 MFMAs), C += tanh(g); one atomic commit/iter.
//  head: MLP + masked reduce.
// Frag maps (m89-verified): A row=l&15, K=(l>>4)*8+e; B col=l&15, same K;
//                           D col=l&15, row=(l>>4)*4+e.
// ---------------------------------------------------------------------------
__global__ __launch_bounds__(256, 2) void mdtnn_one(
    const int* __restrict__ Zg, const float* __restrict__ Dg,
    const int* __restrict__ sizesg, const float* __restrict__ embg,
    const float* __restrict__ dfwg, const float* __restrict__ dfbg,
    const float* __restrict__ cfwg, const float* __restrict__ cfbg,
    const float* __restrict__ fcwg, const float* __restrict__ w1g,
    const float* __restrict__ b1g, const float* __restrict__ w2g,
    const float* __restrict__ b2g, float* __restrict__ outg)
{
  const int b = blockIdx.x, tid = threadIdx.x;
  const int wid = tid >> 6, l = tid & 63;
  const int lr = l & 15, lc = l >> 4;
  const int n = sizesg[b];
  const int nn = n * n;

  __shared__ __align__(16) uint2 dh_s[900 * 8];     // 57.6 KB, [pair][h/4]
  __shared__ __align__(16) float C_lds[32][36];
  __shared__ __align__(16) float X1_lds[32][36];    // 36: 2-way (free) store banks, 16B-aligned rows
  __shared__ __align__(16) float w1_s[32][16];
  __shared__ float b1_s[16], w2_s[16], wsum[4];

  // ---- stage small weights + init C ----
  for (int t = tid; t < 512; t += 256) {
    int k = t >> 4, c = t & 15;
    w1_s[k][c] = (k < 30 && c < 15) ? w1g[k * 15 + c] : 0.f;
  }
  if (tid < 16) {
    b1_s[tid] = (tid < 15) ? b1g[tid] : 0.f;
    w2_s[tid] = (tid < 15) ? w2g[tid] : 0.f;
  }
  for (int t = tid; t < 1024; t += 256) {
    int j = t >> 5, k = t & 31;
    float v = 0.f;
    if (j < n && k < 30) v = embg[Zg[b * 30 + j] * 30 + k];
    C_lds[j][k] = v;
  }

  // ---- phase A: dh -> LDS ----
  {
    // A fragments: dfw^T (row=h, K=g), hi/lo split, zero-padded
    bh8 Ah[2][2], Al[2][2];
    #pragma unroll
    for (int ht = 0; ht < 2; ++ht) {
      const int h = ht * 16 + lr;
      #pragma unroll
      for (int kc = 0; kc < 2; ++kc) {
        #pragma unroll
        for (int e = 0; e < 8; ++e) {
          const int g = kc * 32 + lc * 8 + e;
          float v = (g < 56 && h < 30) ? dfwg[g * 30 + h] : 0.f;
          float hf;
          Ah[ht][kc][e] = bf16hi(v, &hf);
          Al[ht][kc][e] = bf16s(v - hf);
        }
      }
    }
    float dfbv[2][4];
    #pragma unroll
    for (int ht = 0; ht < 2; ++ht)
      #pragma unroll
      for (int e = 0; e < 4; ++e) {
        const int h = ht * 16 + lc * 4 + e;
        dfbv[ht][e] = (h < 30) ? dfbg[h] : 0.f;
      }

    const float* Db = Dg + (size_t)b * (30 * 30 * 56);
    const unsigned inv = (65536u + (unsigned)n - 1) / (unsigned)n;
    const f4 z4 = {0.f, 0.f, 0.f, 0.f};
    const int tiles = (nn + 15) >> 4;
    for (int t = wid; t < tiles; t += 4) {
      const int p_raw = t * 16 + lr;
      const int p = min(p_raw, nn - 1);
      const int i = (int)(((unsigned)p * inv) >> 16);
      const int j = p - i * n;
      const int row = i * 30 + j;
      const float* Dp = Db + (size_t)row * 56;

      float4 q0 = *reinterpret_cast<const float4*>(Dp + lc * 8);
      float4 q1 = *reinterpret_cast<const float4*>(Dp + lc * 8 + 4);
      float4 q2 = {0.f, 0.f, 0.f, 0.f}, q3 = {0.f, 0.f, 0.f, 0.f};
      if (lc < 3) {
        q2 = *reinterpret_cast<const float4*>(Dp + 32 + lc * 8);
        q3 = *reinterpret_cast<const float4*>(Dp + 32 + lc * 8 + 4);
      }
      bh8 B0, B1;
      B0[0] = bf16s(q0.x); B0[1] = bf16s(q0.y); B0[2] = bf16s(q0.z); B0[3] = bf16s(q0.w);
      B0[4] = bf16s(q1.x); B0[5] = bf16s(q1.y); B0[6] = bf16s(q1.z); B0[7] = bf16s(q1.w);
      B1[0] = bf16s(q2.x); B1[1] = bf16s(q2.y); B1[2] = bf16s(q2.z); B1[3] = bf16s(q2.w);
      B1[4] = bf16s(q3.x); B1[5] = bf16s(q3.y); B1[6] = bf16s(q3.z); B1[7] = bf16s(q3.w);

      f4 a0 = z4, a1 = z4;
      a0 = MFMA_BF16(Al[0][0], B0, a0, 0, 0, 0);
      a0 = MFMA_BF16(Ah[0][0], B0, a0, 0, 0, 0);
      a0 = MFMA_BF16(Al[0][1], B1, a0, 0, 0, 0);
      a0 = MFMA_BF16(Ah[0][1], B1, a0, 0, 0, 0);
      a1 = MFMA_BF16(Al[1][0], B0, a1, 0, 0, 0);
      a1 = MFMA_BF16(Ah[1][0], B0, a1, 0, 0, 0);
      a1 = MFMA_BF16(Al[1][1], B1, a1, 0, 0, 0);
      a1 = MFMA_BF16(Ah[1][1], B1, a1, 0, 0, 0);

      if (p_raw < nn) {
        uint2 s0, s1;
        s0.x = pack2_bf16(a0[0] + dfbv[0][0], a0[1] + dfbv[0][1]);
        s0.y = pack2_bf16(a0[2] + dfbv[0][2], a0[3] + dfbv[0][3]);
        s1.x = pack2_bf16(a1[0] + dfbv[1][0], a1[1] + dfbv[1][1]);
        s1.y = pack2_bf16(a1[2] + dfbv[1][2], a1[3] + dfbv[1][3]);
        dh_s[row * 8 + 0 * 4 + lc] = s0;   // h = lc*4 .. +3
        dh_s[row * 8 + 1 * 4 + lc] = s1;   // h = 16 + lc*4 .. +3
      }
    }
  }

  // ---- per-lane weight fragments for the iteration loop ----
  float fcwF0[8], fcwF1[8];
  bh8 cfwB0h, cfwB0l, cfwB1h, cfwB1l;
  #pragma unroll
  for (int e = 0; e < 8; ++e) {
    const int kk = lc * 8 + e;
    const int c1 = lr + 16;
    fcwF0[e] = (kk < 30) ? fcwg[kk * 30 + lr] : 0.f;
    fcwF1[e] = (kk < 30 && c1 < 30) ? fcwg[kk * 30 + c1] : 0.f;
    float g0 = (kk < 30) ? cfwg[kk * 30 + lr] : 0.f;
    float g1 = (kk < 30 && c1 < 30) ? cfwg[kk * 30 + c1] : 0.f;
    float hf;
    cfwB0h[e] = bf16hi(g0, &hf);
    cfwB0l[e] = bf16s(g0 - hf);
    cfwB1h[e] = bf16hi(g1, &hf);
    cfwB1l[e] = bf16s(g1 - hf);
  }
  const float cfb0 = cfbg[lr];
  const float cfb1 = (lr + 16 < 30) ? cfbg[lr + 16] : 0.f;
  const f4 z4 = {0.f, 0.f, 0.f, 0.f};

  __syncthreads();   // dh_s + C_lds ready

  // ---- 3 message-passing iterations ----
  for (int it = 0; it < 3; ++it) {
    if (wid < 2) {   // X1 rows [wid*16, wid*16+16)
      const int row = wid * 16 + lr;
      float cv[8];
      *reinterpret_cast<float4*>(&cv[0]) =
          *reinterpret_cast<const float4*>(&C_lds[row][lc * 8]);
      *reinterpret_cast<float4*>(&cv[4]) =
          *reinterpret_cast<const float4*>(&C_lds[row][lc * 8 + 4]);
      bh8 Ch, Cl;
      #pragma unroll
      for (int e = 0; e < 8; ++e) {
        float hf;
        Ch[e] = bf16hi(cv[e], &hf);
        Cl[e] = bf16s(cv[e] - hf);
      }
      f4 d0 = MFMA_BF16(Ch, cfwB0l, z4, 0, 0, 0);
      d0 = MFMA_BF16(Cl, cfwB0h, d0, 0, 0, 0);
      d0 = MFMA_BF16(Ch, cfwB0h, d0, 0, 0, 0);
      f4 d1 = MFMA_BF16(Ch, cfwB1l, z4, 0, 0, 0);
      d1 = MFMA_BF16(Cl, cfwB1h, d1, 0, 0, 0);
      d1 = MFMA_BF16(Ch, cfwB1h, d1, 0, 0, 0);
      #pragma unroll
      for (int e = 0; e < 4; ++e) {
        int r = wid * 16 + lc * 4 + e;
        X1_lds[r][lr] = d0[e] + cfb0;
        X1_lds[r][lr + 16] = d1[e] + cfb1;
      }
    }
    __syncthreads();

    f4 inc00 = z4, inc01 = z4, inc10 = z4, inc11 = z4;
    for (int i = wid; i < n; i += 4) {
      uint4 a0c = {0, 0, 0, 0}, a1c = {0, 0, 0, 0};
      if (lr < n)
        a0c = *reinterpret_cast<const uint4*>(&dh_s[(i * 30 + lr) * 8 + lc * 2]);
      if (lr + 16 < n)
        a1c = *reinterpret_cast<const uint4*>(&dh_s[(i * 30 + lr + 16) * 8 + lc * 2]);

      float4 xA = *reinterpret_cast<const float4*>(&X1_lds[i][lc * 8]);
      float4 xB = *reinterpret_cast<const float4*>(&X1_lds[i][lc * 8 + 4]);
      float xv[8] = {xA.x, xA.y, xA.z, xA.w, xB.x, xB.y, xB.z, xB.w};
      bh8 W0h, W0l, W1h, W1l;
      #pragma unroll
      for (int e = 0; e < 8; ++e) {
        float p0 = xv[e] * fcwF0[e];
        float p1 = xv[e] * fcwF1[e];
        float hf;
        W0h[e] = bf16hi(p0, &hf);
        W0l[e] = bf16s(p0 - hf);
        W1h[e] = bf16hi(p1, &hf);
        W1l[e] = bf16s(p1 - hf);
      }
      const bh8 A0 = *reinterpret_cast<const bh8*>(&a0c);
      const bh8 A1 = *reinterpret_cast<const bh8*>(&a1c);
      f4 g;
      g = MFMA_BF16(A0, W0l, z4, 0, 0, 0);
      g = MFMA_BF16(A0, W0h, g, 0, 0, 0);
      #pragma unroll
      for (int e = 0; e < 4; ++e) inc00[e] += fast_tanh(g[e]);
      g = MFMA_BF16(A0, W1l, z4, 0, 0, 0);
      g = MFMA_BF16(A0, W1h, g, 0, 0, 0);
      #pragma unroll
      for (int e = 0; e < 4; ++e) inc01[e] += fast_tanh(g[e]);
      g = MFMA_BF16(A1, W0l, z4, 0, 0, 0);
      g = MFMA_BF16(A1, W0h, g, 0, 0, 0);
      #pragma unroll
      for (int e = 0; e < 4; ++e) inc10[e] += fast_tanh(g[e]);
      g = MFMA_BF16(A1, W1l, z4, 0, 0, 0);
      g = MFMA_BF16(A1, W1h, g, 0, 0, 0);
      #pragma unroll
      for (int e = 0; e < 4; ++e) inc11[e] += fast_tanh(g[e]);
    }
    #pragma unroll
    for (int e = 0; e < 4; ++e) {
      atomicAdd(&C_lds[lc * 4 + e][lr], inc00[e]);
      atomicAdd(&C_lds[lc * 4 + e][lr + 16], inc01[e]);
      atomicAdd(&C_lds[16 + lc * 4 + e][lr], inc10[e]);
      atomicAdd(&C_lds[16 + lc * 4 + e][lr + 16], inc11[e]);
    }
    __syncthreads();
  }

  // ---- MLP head + masked reduce ----
  float esum = 0.f;
  for (int t = tid; t < n * 16; t += 256) {
    int j = t >> 4, c = t & 15;
    if (c < 15) {
      float a = b1_s[c];
      #pragma unroll
      for (int kc = 0; kc < 8; ++kc) {
        float4 c4 = *reinterpret_cast<const float4*>(&C_lds[j][kc * 4]);
        a = fmaf(c4.x, w1_s[kc * 4 + 0][c], a);
        a = fmaf(c4.y, w1_s[kc * 4 + 1][c], a);
        a = fmaf(c4.z, w1_s[kc * 4 + 2][c], a);
        a = fmaf(c4.w, w1_s[kc * 4 + 3][c], a);
      }
      esum += fast_tanh(a) * w2_s[c];
    }
  }
  #pragma unroll
  for (int off = 32; off; off >>= 1) esum += __shfl_down(esum, off);
  if (l == 0) wsum[wid] = esum;
  __syncthreads();
  if (tid == 0)
    outg[b] = wsum[0] + wsum[1] + wsum[2] + wsum[3] + (float)n * b2g[0];
}

extern "C" void kernel_launch(void* const* d_in, const int* in_sizes, int n_in,
                              void* d_out, int out_size, void* d_ws, size_t ws_size,
                              hipStream_t stream) {
  (void)in_sizes; (void)n_in; (void)d_ws; (void)ws_size;
  const int*   Z   = (const int*)d_in[0];
  const float* D   = (const float*)d_in[1];
  const int*   sz  = (const int*)d_in[2];
  const float* emb = (const float*)d_in[3];
  const float* dfw = (const float*)d_in[4];
  const float* dfb = (const float*)d_in[5];
  const float* cfw = (const float*)d_in[6];
  const float* cfb = (const float*)d_in[7];
  const float* fcw = (const float*)d_in[8];
  const float* w1  = (const float*)d_in[9];
  const float* b1  = (const float*)d_in[10];
  const float* w2  = (const float*)d_in[11];
  const float* b2  = (const float*)d_in[12];
  float* out = (float*)d_out;
  const int B = out_size;  // 2048 molecules, one block each

  mdtnn_one<<<dim3(B), dim3(256), 0, stream>>>(Z, D, sz, emb, dfw, dfb, cfw, cfb,
                                               fcw, w1, b1, w2, b2, out);
}

// Round 9
// 215.358 us; speedup vs baseline: 1.0254x; 1.0254x over previous
//
#include <hip/hip_runtime.h>
#include <hip/hip_bf16.h>

typedef __attribute__((ext_vector_type(8))) short bh8;   // 8 x bf16 (4 VGPR) MFMA A/B frag
typedef __attribute__((ext_vector_type(4))) float f4;    // 4 x f32 MFMA C/D frag

#define MFMA_BF16 __builtin_amdgcn_mfma_f32_16x16x32_bf16

__device__ __forceinline__ float fast_tanh(float x) {
  float cl = fminf(fmaxf(x, -15.f), 15.f);
  float e = __builtin_amdgcn_exp2f(cl * 2.885390081777927f);  // exp(2x)
  return (e - 1.f) * __builtin_amdgcn_rcpf(e + 1.f);
}

// scalar cast -> compiler emits v_cvt_pk_bf16_f32 for pairs (m240)
__device__ __forceinline__ short bf16hi(float f, float* hf) {
  __hip_bfloat16 h = __float2bfloat16(f);
  *hf = __bfloat162float(h);
  short s;
  __builtin_memcpy(&s, &h, 2);
  return s;
}
__device__ __forceinline__ short bf16s(float f) {
  __hip_bfloat16 h = __float2bfloat16(f);
  short s;
  __builtin_memcpy(&s, &h, 2);
  return s;
}

__device__ __forceinline__ unsigned pack2_bf16(float a, float b) {
  unsigned ua = __float_as_uint(a);
  unsigned ub = __float_as_uint(b);
  ua = (ua + 0x7fffu + ((ua >> 16) & 1u)) >> 16;
  ub = (ub + 0x7fffu + ((ub >> 16) & 1u)) & 0xffff0000u;
  return ua | ub;
}

// d_hat layout: [b][i(30)][j(30)][h(32, bf16)] -> 64 B per (i,j) pair.

// ---------------------------------------------------------------------------
// Phase A (MFMA, unchanged from R7): d_hat = D @ df_w + df_b -> global bf16.
// ---------------------------------------------------------------------------
__global__ __launch_bounds__(256, 4) void mdtnn_phA_mfma(
    const float* __restrict__ Dg, const int* __restrict__ sizesg,
    const float* __restrict__ dfwg, const float* __restrict__ dfbg,
    uint2* __restrict__ dhg)
{
  const int b = blockIdx.x, tid = threadIdx.x;
  const int w = tid >> 6, l = tid & 63;
  const int lr = l & 15, lc = l >> 4;
  const int n = sizesg[b];
  const int nn = n * n;
  const unsigned inv = (65536u + (unsigned)n - 1) / (unsigned)n;  // exact p/n for p<1024

  bh8 Ah[2][2], Al[2][2];
  #pragma unroll
  for (int ht = 0; ht < 2; ++ht) {
    const int h = ht * 16 + lr;
    #pragma unroll
    for (int kc = 0; kc < 2; ++kc) {
      #pragma unroll
      for (int e = 0; e < 8; ++e) {
        const int g = kc * 32 + lc * 8 + e;
        float v = (g < 56 && h < 30) ? dfwg[g * 30 + h] : 0.f;
        float hf;
        Ah[ht][kc][e] = bf16hi(v, &hf);
        Al[ht][kc][e] = bf16s(v - hf);
      }
    }
  }
  float dfbv[2][4];
  #pragma unroll
  for (int ht = 0; ht < 2; ++ht)
    #pragma unroll
    for (int e = 0; e < 4; ++e) {
      const int h = ht * 16 + lc * 4 + e;
      dfbv[ht][e] = (h < 30) ? dfbg[h] : 0.f;
    }

  const float* Db = Dg + (size_t)b * (30 * 30 * 56);
  uint2* dhb = dhg + (size_t)b * (30 * 30 * 8);
  const f4 z4 = {0.f, 0.f, 0.f, 0.f};

  const int tiles = (nn + 15) >> 4;
  for (int t = w; t < tiles; t += 4) {
    const int p_raw = t * 16 + lr;
    const int p = min(p_raw, nn - 1);
    const int i = (int)(((unsigned)p * inv) >> 16);
    const int j = p - i * n;
    const int row = i * 30 + j;
    const float* Dp = Db + (size_t)row * 56;

    float4 q0 = *reinterpret_cast<const float4*>(Dp + lc * 8);
    float4 q1 = *reinterpret_cast<const float4*>(Dp + lc * 8 + 4);
    float4 q2 = {0.f, 0.f, 0.f, 0.f}, q3 = {0.f, 0.f, 0.f, 0.f};
    if (lc < 3) {
      q2 = *reinterpret_cast<const float4*>(Dp + 32 + lc * 8);
      q3 = *reinterpret_cast<const float4*>(Dp + 32 + lc * 8 + 4);
    }
    bh8 B0, B1;
    B0[0] = bf16s(q0.x); B0[1] = bf16s(q0.y); B0[2] = bf16s(q0.z); B0[3] = bf16s(q0.w);
    B0[4] = bf16s(q1.x); B0[5] = bf16s(q1.y); B0[6] = bf16s(q1.z); B0[7] = bf16s(q1.w);
    B1[0] = bf16s(q2.x); B1[1] = bf16s(q2.y); B1[2] = bf16s(q2.z); B1[3] = bf16s(q2.w);
    B1[4] = bf16s(q3.x); B1[5] = bf16s(q3.y); B1[6] = bf16s(q3.z); B1[7] = bf16s(q3.w);

    f4 a0 = z4, a1 = z4;
    a0 = MFMA_BF16(Al[0][0], B0, a0, 0, 0, 0);
    a0 = MFMA_BF16(Ah[0][0], B0, a0, 0, 0, 0);
    a0 = MFMA_BF16(Al[0][1], B1, a0, 0, 0, 0);
    a0 = MFMA_BF16(Ah[0][1], B1, a0, 0, 0, 0);
    a1 = MFMA_BF16(Al[1][0], B0, a1, 0, 0, 0);
    a1 = MFMA_BF16(Ah[1][0], B0, a1, 0, 0, 0);
    a1 = MFMA_BF16(Al[1][1], B1, a1, 0, 0, 0);
    a1 = MFMA_BF16(Ah[1][1], B1, a1, 0, 0, 0);

    if (p_raw < nn) {
      uint2 s0, s1;
      s0.x = pack2_bf16(a0[0] + dfbv[0][0], a0[1] + dfbv[0][1]);
      s0.y = pack2_bf16(a0[2] + dfbv[0][2], a0[3] + dfbv[0][3]);
      s1.x = pack2_bf16(a1[0] + dfbv[1][0], a1[1] + dfbv[1][1]);
      s1.y = pack2_bf16(a1[2] + dfbv[1][2], a1[3] + dfbv[1][3]);
      dhb[row * 8 + 0 * 4 + lc] = s0;
      dhb[row * 8 + 1 * 4 + lc] = s1;
    }
  }
}

// ---------------------------------------------------------------------------
// Phase B v2: one molecule per 256-thread block (4 waves), i split 4 ways.
//   X1 = (Ch+Cl)@(cfwH+cfwL)+cfb   (waves 0-1, 6 MFMAs each — hi/lo KEPT)
//   per i: W' = bf16(X1[i] * fc_w)  (single rounding; 4 MFMAs per i-step)
//          g = dh[i] @ W'; C += tanh(g); one LDS-atomic commit per iteration
// Frag maps (m89-verified): A row=l&15, K=(l>>4)*8+e; B col=l&15, same K;
//                           D col=l&15, row=(l>>4)*4+e.
// ---------------------------------------------------------------------------
__global__ __launch_bounds__(256, 4) void mdtnn_phB2(
    const int* __restrict__ Zg, const int* __restrict__ sizesg,
    const float* __restrict__ embg, const float* __restrict__ cfwg,
    const float* __restrict__ cfbg, const float* __restrict__ fcwg,
    const float* __restrict__ w1g, const float* __restrict__ b1g,
    const float* __restrict__ w2g, const float* __restrict__ b2g,
    const unsigned* __restrict__ dhg, float* __restrict__ outg)
{
  const int b = blockIdx.x, tid = threadIdx.x;
  const int wid = tid >> 6, l = tid & 63;
  const int lr = l & 15, lc = l >> 4;
  const int n = sizesg[b];

  __shared__ __align__(16) float C_lds[32][36];
  __shared__ __align__(16) float X1_lds[32][36];
  __shared__ __align__(16) float w1_s[32][16];
  __shared__ float b1_s[16], w2_s[16], wsum[4];

  for (int t = tid; t < 512; t += 256) {
    int k = t >> 4, c = t & 15;
    w1_s[k][c] = (k < 30 && c < 15) ? w1g[k * 15 + c] : 0.f;
  }
  if (tid < 16) {
    b1_s[tid] = (tid < 15) ? b1g[tid] : 0.f;
    w2_s[tid] = (tid < 15) ? w2g[tid] : 0.f;
  }
  for (int t = tid; t < 1024; t += 256) {
    int j = t >> 5, k = t & 31;
    float v = 0.f;
    if (j < n && k < 30) v = embg[Zg[b * 30 + j] * 30 + k];
    C_lds[j][k] = v;
  }

  // per-lane weight state (contraction index kk = lc*8+e)
  float fcwF0[8], fcwF1[8];
  bh8 cfwB0h, cfwB0l, cfwB1h, cfwB1l;
  #pragma unroll
  for (int e = 0; e < 8; ++e) {
    const int kk = lc * 8 + e;
    const int c1 = lr + 16;
    fcwF0[e] = (kk < 30) ? fcwg[kk * 30 + lr] : 0.f;
    fcwF1[e] = (kk < 30 && c1 < 30) ? fcwg[kk * 30 + c1] : 0.f;
    float g0 = (kk < 30) ? cfwg[kk * 30 + lr] : 0.f;
    float g1 = (kk < 30 && c1 < 30) ? cfwg[kk * 30 + c1] : 0.f;
    float hf;
    cfwB0h[e] = bf16hi(g0, &hf);
    cfwB0l[e] = bf16s(g0 - hf);
    cfwB1h[e] = bf16hi(g1, &hf);
    cfwB1l[e] = bf16s(g1 - hf);
  }
  const float cfb0 = cfbg[lr];
  const float cfb1 = (lr + 16 < 30) ? cfbg[lr + 16] : 0.f;

  const unsigned* dhb = dhg + (size_t)b * (30 * 30 * 16);  // dwords
  const f4 z4 = {0.f, 0.f, 0.f, 0.f};

  __syncthreads();

  for (int it = 0; it < 3; ++it) {
    // ---- X1 rows (waves 0-1; full hi/lo split for accuracy) ----
    if (wid < 2) {
      const int row = wid * 16 + lr;
      float cv[8];
      *reinterpret_cast<float4*>(&cv[0]) =
          *reinterpret_cast<const float4*>(&C_lds[row][lc * 8]);
      *reinterpret_cast<float4*>(&cv[4]) =
          *reinterpret_cast<const float4*>(&C_lds[row][lc * 8 + 4]);
      bh8 Ch, Cl;
      #pragma unroll
      for (int e = 0; e < 8; ++e) {
        float hf;
        Ch[e] = bf16hi(cv[e], &hf);
        Cl[e] = bf16s(cv[e] - hf);
      }
      f4 d0 = MFMA_BF16(Ch, cfwB0l, z4, 0, 0, 0);
      d0 = MFMA_BF16(Cl, cfwB0h, d0, 0, 0, 0);
      d0 = MFMA_BF16(Ch, cfwB0h, d0, 0, 0, 0);
      f4 d1 = MFMA_BF16(Ch, cfwB1l, z4, 0, 0, 0);
      d1 = MFMA_BF16(Cl, cfwB1h, d1, 0, 0, 0);
      d1 = MFMA_BF16(Ch, cfwB1h, d1, 0, 0, 0);
      #pragma unroll
      for (int e = 0; e < 4; ++e) {
        int r = wid * 16 + lc * 4 + e;
        X1_lds[r][lr] = d0[e] + cfb0;
        X1_lds[r][lr + 16] = d1[e] + cfb1;
      }
    }
    __syncthreads();

    // ---- accumulate: wave handles i = wid, wid+4, ... (one-ahead prefetch) ----
    f4 inc00 = z4, inc01 = z4, inc10 = z4, inc11 = z4;
    {
      uint4 a0c = {0, 0, 0, 0}, a1c = {0, 0, 0, 0};
      if (wid < n) {
        const unsigned* p = dhb + (size_t)wid * 480;
        if (lr < n) a0c = *reinterpret_cast<const uint4*>(p + lr * 16 + lc * 4);
        if (lr + 16 < n) a1c = *reinterpret_cast<const uint4*>(p + lr * 16 + 256 + lc * 4);
      }
      for (int i = wid; i < n; i += 4) {
        uint4 a0n = {0, 0, 0, 0}, a1n = {0, 0, 0, 0};
        if (i + 4 < n) {
          const unsigned* p = dhb + (size_t)(i + 4) * 480;
          if (lr < n) a0n = *reinterpret_cast<const uint4*>(p + lr * 16 + lc * 4);
          if (lr + 16 < n) a1n = *reinterpret_cast<const uint4*>(p + lr * 16 + 256 + lc * 4);
        }
        float4 xA = *reinterpret_cast<const float4*>(&X1_lds[i][lc * 8]);
        float4 xB = *reinterpret_cast<const float4*>(&X1_lds[i][lc * 8 + 4]);
        float xv[8] = {xA.x, xA.y, xA.z, xA.w, xB.x, xB.y, xB.z, xB.w};
        bh8 W0, W1;
        #pragma unroll
        for (int e = 0; e < 8; ++e) {
          W0[e] = bf16s(xv[e] * fcwF0[e]);
          W1[e] = bf16s(xv[e] * fcwF1[e]);
        }
        const bh8 A0 = *reinterpret_cast<const bh8*>(&a0c);
        const bh8 A1 = *reinterpret_cast<const bh8*>(&a1c);
        f4 g;
        g = MFMA_BF16(A0, W0, z4, 0, 0, 0);
        #pragma unroll
        for (int e = 0; e < 4; ++e) inc00[e] += fast_tanh(g[e]);
        g = MFMA_BF16(A0, W1, z4, 0, 0, 0);
        #pragma unroll
        for (int e = 0; e < 4; ++e) inc01[e] += fast_tanh(g[e]);
        g = MFMA_BF16(A1, W0, z4, 0, 0, 0);
        #pragma unroll
        for (int e = 0; e < 4; ++e) inc10[e] += fast_tanh(g[e]);
        g = MFMA_BF16(A1, W1, z4, 0, 0, 0);
        #pragma unroll
        for (int e = 0; e < 4; ++e) inc11[e] += fast_tanh(g[e]);
        a0c = a0n;
        a1c = a1n;
      }
    }
    #pragma unroll
    for (int e = 0; e < 4; ++e) {
      atomicAdd(&C_lds[lc * 4 + e][lr], inc00[e]);
      atomicAdd(&C_lds[lc * 4 + e][lr + 16], inc01[e]);
      atomicAdd(&C_lds[16 + lc * 4 + e][lr], inc10[e]);
      atomicAdd(&C_lds[16 + lc * 4 + e][lr + 16], inc11[e]);
    }
    __syncthreads();
  }

  // ---- MLP head + masked reduce ----
  float esum = 0.f;
  for (int t = tid; t < n * 16; t += 256) {
    int j = t >> 4, c = t & 15;
    if (c < 15) {
      float a = b1_s[c];
      #pragma unroll
      for (int kc = 0; kc < 8; ++kc) {
        float4 c4 = *reinterpret_cast<const float4*>(&C_lds[j][kc * 4]);
        a = fmaf(c4.x, w1_s[kc * 4 + 0][c], a);
        a = fmaf(c4.y, w1_s[kc * 4 + 1][c], a);
        a = fmaf(c4.z, w1_s[kc * 4 + 2][c], a);
        a = fmaf(c4.w, w1_s[kc * 4 + 3][c], a);
      }
      esum += fast_tanh(a) * w2_s[c];
    }
  }
  #pragma unroll
  for (int off = 32; off; off >>= 1) esum += __shfl_down(esum, off);
  if (l == 0) wsum[wid] = esum;
  __syncthreads();
  if (tid == 0)
    outg[b] = wsum[0] + wsum[1] + wsum[2] + wsum[3] + (float)n * b2g[0];
}

extern "C" void kernel_launch(void* const* d_in, const int* in_sizes, int n_in,
                              void* d_out, int out_size, void* d_ws, size_t ws_size,
                              hipStream_t stream) {
  (void)in_sizes; (void)n_in; (void)ws_size;
  const int*   Z   = (const int*)d_in[0];
  const float* D   = (const float*)d_in[1];
  const int*   sz  = (const int*)d_in[2];
  const float* emb = (const float*)d_in[3];
  const float* dfw = (const float*)d_in[4];
  const float* dfb = (const float*)d_in[5];
  const float* cfw = (const float*)d_in[6];
  const float* cfb = (const float*)d_in[7];
  const float* fcw = (const float*)d_in[8];
  const float* w1  = (const float*)d_in[9];
  const float* b1  = (const float*)d_in[10];
  const float* w2  = (const float*)d_in[11];
  const float* b2  = (const float*)d_in[12];
  float* out = (float*)d_out;
  const int B = out_size;  // 2048

  // ws_size has held >=118MB all rounds (phA/phB kernels visible in rocprof).
  mdtnn_phA_mfma<<<dim3(B), dim3(256), 0, stream>>>(D, sz, dfw, dfb, (uint2*)d_ws);
  mdtnn_phB2<<<dim3(B), dim3(256), 0, stream>>>(Z, sz, emb, cfw, cfb, fcw,
                                                w1, b1, w2, b2,
                                                (const unsigned*)d_ws, out);
}

// Round 10
// 123.225 us; speedup vs baseline: 1.7921x; 1.7477x over previous
//
#include <hip/hip_runtime.h>
#include <hip/hip_bf16.h>

typedef __attribute__((ext_vector_type(8))) short bh8;   // 8 x bf16 (4 VGPR) MFMA A/B frag
typedef __attribute__((ext_vector_type(4))) float f4;    // 4 x f32 MFMA C/D frag

#define MFMA_BF16 __builtin_amdgcn_mfma_f32_16x16x32_bf16

__device__ __forceinline__ float fast_tanh(float x) {
  float cl = fminf(fmaxf(x, -15.f), 15.f);
  float e = __builtin_amdgcn_exp2f(cl * 2.885390081777927f);  // exp(2x)
  return (e - 1.f) * __builtin_amdgcn_rcpf(e + 1.f);
}

__device__ __forceinline__ short bf16hi(float f, float* hf) {
  __hip_bfloat16 h = __float2bfloat16(f);
  *hf = __bfloat162float(h);
  short s;
  __builtin_memcpy(&s, &h, 2);
  return s;
}
__device__ __forceinline__ short bf16s(float f) {
  __hip_bfloat16 h = __float2bfloat16(f);
  short s;
  __builtin_memcpy(&s, &h, 2);
  return s;
}

__device__ __forceinline__ unsigned pack2_bf16(float a, float b) {
  unsigned ua = __float_as_uint(a);
  unsigned ub = __float_as_uint(b);
  ua = (ua + 0x7fffu + ((ua >> 16) & 1u)) >> 16;
  ub = (ub + 0x7fffu + ((ub >> 16) & 1u)) & 0xffff0000u;
  return ua | ub;
}

// d_hat layout: [b][i(30)][j(30)][h(32, bf16)] -> 64 B per (i,j) pair.

// ---------------------------------------------------------------------------
// Phase A (MFMA, unchanged since R7 — validated): d_hat = D@df_w+df_b -> global.
// ---------------------------------------------------------------------------
__global__ __launch_bounds__(256, 4) void mdtnn_phA_mfma(
    const float* __restrict__ Dg, const int* __restrict__ sizesg,
    const float* __restrict__ dfwg, const float* __restrict__ dfbg,
    uint2* __restrict__ dhg)
{
  const int b = blockIdx.x, tid = threadIdx.x;
  const int w = tid >> 6, l = tid & 63;
  const int lr = l & 15, lc = l >> 4;
  const int n = sizesg[b];
  const int nn = n * n;
  const unsigned inv = (65536u + (unsigned)n - 1) / (unsigned)n;  // exact p/n for p<1024

  bh8 Ah[2][2], Al[2][2];
  #pragma unroll
  for (int ht = 0; ht < 2; ++ht) {
    const int h = ht * 16 + lr;
    #pragma unroll
    for (int kc = 0; kc < 2; ++kc) {
      #pragma unroll
      for (int e = 0; e < 8; ++e) {
        const int g = kc * 32 + lc * 8 + e;
        float v = (g < 56 && h < 30) ? dfwg[g * 30 + h] : 0.f;
        float hf;
        Ah[ht][kc][e] = bf16hi(v, &hf);
        Al[ht][kc][e] = bf16s(v - hf);
      }
    }
  }
  float dfbv[2][4];
  #pragma unroll
  for (int ht = 0; ht < 2; ++ht)
    #pragma unroll
    for (int e = 0; e < 4; ++e) {
      const int h = ht * 16 + lc * 4 + e;
      dfbv[ht][e] = (h < 30) ? dfbg[h] : 0.f;
    }

  const float* Db = Dg + (size_t)b * (30 * 30 * 56);
  uint2* dhb = dhg + (size_t)b * (30 * 30 * 8);
  const f4 z4 = {0.f, 0.f, 0.f, 0.f};

  const int tiles = (nn + 15) >> 4;
  for (int t = w; t < tiles; t += 4) {
    const int p_raw = t * 16 + lr;
    const int p = min(p_raw, nn - 1);
    const int i = (int)(((unsigned)p * inv) >> 16);
    const int j = p - i * n;
    const int row = i * 30 + j;
    const float* Dp = Db + (size_t)row * 56;

    float4 q0 = *reinterpret_cast<const float4*>(Dp + lc * 8);
    float4 q1 = *reinterpret_cast<const float4*>(Dp + lc * 8 + 4);
    float4 q2 = {0.f, 0.f, 0.f, 0.f}, q3 = {0.f, 0.f, 0.f, 0.f};
    if (lc < 3) {
      q2 = *reinterpret_cast<const float4*>(Dp + 32 + lc * 8);
      q3 = *reinterpret_cast<const float4*>(Dp + 32 + lc * 8 + 4);
    }
    bh8 B0, B1;
    B0[0] = bf16s(q0.x); B0[1] = bf16s(q0.y); B0[2] = bf16s(q0.z); B0[3] = bf16s(q0.w);
    B0[4] = bf16s(q1.x); B0[5] = bf16s(q1.y); B0[6] = bf16s(q1.z); B0[7] = bf16s(q1.w);
    B1[0] = bf16s(q2.x); B1[1] = bf16s(q2.y); B1[2] = bf16s(q2.z); B1[3] = bf16s(q2.w);
    B1[4] = bf16s(q3.x); B1[5] = bf16s(q3.y); B1[6] = bf16s(q3.z); B1[7] = bf16s(q3.w);

    f4 a0 = z4, a1 = z4;
    a0 = MFMA_BF16(Al[0][0], B0, a0, 0, 0, 0);
    a0 = MFMA_BF16(Ah[0][0], B0, a0, 0, 0, 0);
    a0 = MFMA_BF16(Al[0][1], B1, a0, 0, 0, 0);
    a0 = MFMA_BF16(Ah[0][1], B1, a0, 0, 0, 0);
    a1 = MFMA_BF16(Al[1][0], B0, a1, 0, 0, 0);
    a1 = MFMA_BF16(Ah[1][0], B0, a1, 0, 0, 0);
    a1 = MFMA_BF16(Al[1][1], B1, a1, 0, 0, 0);
    a1 = MFMA_BF16(Ah[1][1], B1, a1, 0, 0, 0);

    if (p_raw < nn) {
      uint2 s0, s1;
      s0.x = pack2_bf16(a0[0] + dfbv[0][0], a0[1] + dfbv[0][1]);
      s0.y = pack2_bf16(a0[2] + dfbv[0][2], a0[3] + dfbv[0][3]);
      s1.x = pack2_bf16(a1[0] + dfbv[1][0], a1[1] + dfbv[1][1]);
      s1.y = pack2_bf16(a1[2] + dfbv[1][2], a1[3] + dfbv[1][3]);
      dhb[row * 8 + 0 * 4 + lc] = s0;
      dhb[row * 8 + 1 * 4 + lc] = s1;
    }
  }
}

// ---------------------------------------------------------------------------
// Phase B v3: ONE WAVE = ONE MOLECULE. 4 molecules per 256-thread block.
// C lives in 4x f4 registers (D-frag layout: quadrant q, row=16*(q>>1)+lc*4+e,
// col=16*(q&1)+lr). Per iteration:
//   spill C -> wave-private LDS buf (plain stores) -> read as A-frags ->
//   12 MFMAs -> X1 D-frags -> write to same buf -> i-loop over ALL i
//   (one-ahead dh prefetch, W' = bf16(X1*fcw) single-rounded [validated R9],
//    4 MFMAs + 16 tanh, accumulate into C regs).
// NO __syncthreads after staging, NO atomics, no inter-wave coupling.
// ---------------------------------------------------------------------------
__global__ __launch_bounds__(256, 4) void mdtnn_phB3(
    const int* __restrict__ Zg, const int* __restrict__ sizesg,
    const float* __restrict__ embg, const float* __restrict__ cfwg,
    const float* __restrict__ cfbg, const float* __restrict__ fcwg,
    const float* __restrict__ w1g, const float* __restrict__ b1g,
    const float* __restrict__ w2g, const float* __restrict__ b2g,
    const unsigned* __restrict__ dhg, float* __restrict__ outg, int Bn)
{
  const int tid = threadIdx.x;
  const int wid = tid >> 6, l = tid & 63;
  const int lr = l & 15, lc = l >> 4;
  const int bm = blockIdx.x * 4 + wid;   // molecule owned by this wave

  __shared__ __align__(16) float buf[4][32][36];   // wave-private transpose buf
  __shared__ __align__(16) float w1_s[32][16];
  __shared__ float b1_s[16], w2_s[16];

  for (int t = tid; t < 512; t += 256) {
    int k = t >> 4, c = t & 15;
    w1_s[k][c] = (k < 30 && c < 15) ? w1g[k * 15 + c] : 0.f;
  }
  if (tid < 16) {
    b1_s[tid] = (tid < 15) ? b1g[tid] : 0.f;
    w2_s[tid] = (tid < 15) ? w2g[tid] : 0.f;
  }
  __syncthreads();              // only barrier in the kernel
  if (bm >= Bn) return;

  const int n = sizesg[bm];
  float (*mybuf)[36] = buf[wid];

  // per-lane weights (contraction index kk = lc*8+e)
  float fcwF0[8], fcwF1[8];
  bh8 cfwB0h, cfwB0l, cfwB1h, cfwB1l;
  #pragma unroll
  for (int e = 0; e < 8; ++e) {
    const int kk = lc * 8 + e;
    const int c1 = lr + 16;
    fcwF0[e] = (kk < 30) ? fcwg[kk * 30 + lr] : 0.f;
    fcwF1[e] = (kk < 30 && c1 < 30) ? fcwg[kk * 30 + c1] : 0.f;
    float g0 = (kk < 30) ? cfwg[kk * 30 + lr] : 0.f;
    float g1 = (kk < 30 && c1 < 30) ? cfwg[kk * 30 + c1] : 0.f;
    float hf;
    cfwB0h[e] = bf16hi(g0, &hf);
    cfwB0l[e] = bf16s(g0 - hf);
    cfwB1h[e] = bf16hi(g1, &hf);
    cfwB1l[e] = bf16s(g1 - hf);
  }
  const float cfb0 = cfbg[lr];
  const float cfb1 = (lr + 16 < 30) ? cfbg[lr + 16] : 0.f;

  // C in registers, D-frag layout
  f4 C00, C01, C10, C11;
  #pragma unroll
  for (int e = 0; e < 4; ++e) {
    const int r0 = lc * 4 + e;          // < 16
    const int r1 = 16 + lc * 4 + e;     // 16..31
    const int z0 = Zg[bm * 30 + r0];
    C00[e] = embg[z0 * 30 + lr];
    C01[e] = (lr + 16 < 30) ? embg[z0 * 30 + lr + 16] : 0.f;
    if (r1 < 30) {
      const int z1 = Zg[bm * 30 + r1];
      C10[e] = embg[z1 * 30 + lr];
      C11[e] = (lr + 16 < 30) ? embg[z1 * 30 + lr + 16] : 0.f;
    } else {
      C10[e] = 0.f;
      C11[e] = 0.f;
    }
  }

  const unsigned* dhb = dhg + (size_t)bm * 14400;   // dwords
  const f4 z4 = {0.f, 0.f, 0.f, 0.f};

  for (int it = 0; it < 3; ++it) {
    // prefetch dh for i=0 (overlaps with X1 compute below)
    uint4 a0c = {0, 0, 0, 0}, a1c = {0, 0, 0, 0};
    if (lr < n)      a0c = *reinterpret_cast<const uint4*>(dhb + lr * 16 + lc * 4);
    if (lr + 16 < n) a1c = *reinterpret_cast<const uint4*>(dhb + lr * 16 + 256 + lc * 4);

    // ---- spill C (D-layout) to wave-private LDS ----
    #pragma unroll
    for (int e = 0; e < 4; ++e) {
      mybuf[lc * 4 + e][lr]           = C00[e];
      mybuf[lc * 4 + e][lr + 16]      = C01[e];
      mybuf[16 + lc * 4 + e][lr]      = C10[e];
      mybuf[16 + lc * 4 + e][lr + 16] = C11[e];
    }
    // ---- read C as A-frags (both row halves) ----
    float cv0[8], cv1[8];
    *reinterpret_cast<float4*>(&cv0[0]) = *reinterpret_cast<const float4*>(&mybuf[lr][lc * 8]);
    *reinterpret_cast<float4*>(&cv0[4]) = *reinterpret_cast<const float4*>(&mybuf[lr][lc * 8 + 4]);
    *reinterpret_cast<float4*>(&cv1[0]) = *reinterpret_cast<const float4*>(&mybuf[16 + lr][lc * 8]);
    *reinterpret_cast<float4*>(&cv1[4]) = *reinterpret_cast<const float4*>(&mybuf[16 + lr][lc * 8 + 4]);
    bh8 Ch0, Cl0, Ch1, Cl1;
    #pragma unroll
    for (int e = 0; e < 8; ++e) {
      float hf;
      Ch0[e] = bf16hi(cv0[e], &hf);
      Cl0[e] = bf16s(cv0[e] - hf);
      Ch1[e] = bf16hi(cv1[e], &hf);
      Cl1[e] = bf16s(cv1[e] - hf);
    }
    // ---- X1 = C @ cf_w (hi/lo split), 12 MFMAs ----
    f4 d00 = MFMA_BF16(Ch0, cfwB0l, z4, 0, 0, 0);
    d00 = MFMA_BF16(Cl0, cfwB0h, d00, 0, 0, 0);
    d00 = MFMA_BF16(Ch0, cfwB0h, d00, 0, 0, 0);
    f4 d01 = MFMA_BF16(Ch0, cfwB1l, z4, 0, 0, 0);
    d01 = MFMA_BF16(Cl0, cfwB1h, d01, 0, 0, 0);
    d01 = MFMA_BF16(Ch0, cfwB1h, d01, 0, 0, 0);
    f4 d10 = MFMA_BF16(Ch1, cfwB0l, z4, 0, 0, 0);
    d10 = MFMA_BF16(Cl1, cfwB0h, d10, 0, 0, 0);
    d10 = MFMA_BF16(Ch1, cfwB0h, d10, 0, 0, 0);
    f4 d11 = MFMA_BF16(Ch1, cfwB1l, z4, 0, 0, 0);
    d11 = MFMA_BF16(Cl1, cfwB1h, d11, 0, 0, 0);
    d11 = MFMA_BF16(Ch1, cfwB1h, d11, 0, 0, 0);
    // ---- write X1 (D-layout) over the buf ----
    #pragma unroll
    for (int e = 0; e < 4; ++e) {
      mybuf[lc * 4 + e][lr]           = d00[e] + cfb0;
      mybuf[lc * 4 + e][lr + 16]      = d01[e] + cfb1;
      mybuf[16 + lc * 4 + e][lr]      = d10[e] + cfb0;
      mybuf[16 + lc * 4 + e][lr + 16] = d11[e] + cfb1;
    }

    // ---- i-loop over ALL i (wave-private, no sync) ----
    f4 i00 = z4, i01 = z4, i10 = z4, i11 = z4;
    for (int i = 0; i < n; ++i) {
      uint4 a0n = {0, 0, 0, 0}, a1n = {0, 0, 0, 0};
      if (i + 1 < n) {
        const unsigned* p = dhb + (i + 1) * 480;
        if (lr < n)      a0n = *reinterpret_cast<const uint4*>(p + lr * 16 + lc * 4);
        if (lr + 16 < n) a1n = *reinterpret_cast<const uint4*>(p + lr * 16 + 256 + lc * 4);
      }
      float4 xA = *reinterpret_cast<const float4*>(&mybuf[i][lc * 8]);
      float4 xB = *reinterpret_cast<const float4*>(&mybuf[i][lc * 8 + 4]);
      float xv[8] = {xA.x, xA.y, xA.z, xA.w, xB.x, xB.y, xB.z, xB.w};
      bh8 W0, W1;
      #pragma unroll
      for (int e = 0; e < 8; ++e) {
        W0[e] = bf16s(xv[e] * fcwF0[e]);
        W1[e] = bf16s(xv[e] * fcwF1[e]);
      }
      const bh8 A0 = *reinterpret_cast<const bh8*>(&a0c);
      const bh8 A1 = *reinterpret_cast<const bh8*>(&a1c);
      f4 g;
      g = MFMA_BF16(A0, W0, z4, 0, 0, 0);
      #pragma unroll
      for (int e = 0; e < 4; ++e) i00[e] += fast_tanh(g[e]);
      g = MFMA_BF16(A0, W1, z4, 0, 0, 0);
      #pragma unroll
      for (int e = 0; e < 4; ++e) i01[e] += fast_tanh(g[e]);
      g = MFMA_BF16(A1, W0, z4, 0, 0, 0);
      #pragma unroll
      for (int e = 0; e < 4; ++e) i10[e] += fast_tanh(g[e]);
      g = MFMA_BF16(A1, W1, z4, 0, 0, 0);
      #pragma unroll
      for (int e = 0; e < 4; ++e) i11[e] += fast_tanh(g[e]);
      a0c = a0n;
      a1c = a1n;
    }
    C00 += i00;
    C01 += i01;
    C10 += i10;
    C11 += i11;
  }

  // ---- head: spill C, per-lane MLP tasks, wave reduce ----
  #pragma unroll
  for (int e = 0; e < 4; ++e) {
    mybuf[lc * 4 + e][lr]           = C00[e];
    mybuf[lc * 4 + e][lr + 16]      = C01[e];
    mybuf[16 + lc * 4 + e][lr]      = C10[e];
    mybuf[16 + lc * 4 + e][lr + 16] = C11[e];
  }
  float esum = 0.f;
  for (int t = l; t < n * 16; t += 64) {
    int j = t >> 4, c = t & 15;
    if (c < 15) {
      float a = b1_s[c];
      #pragma unroll
      for (int kc = 0; kc < 8; ++kc) {
        float4 c4 = *reinterpret_cast<const float4*>(&mybuf[j][kc * 4]);
        a = fmaf(c4.x, w1_s[kc * 4 + 0][c], a);
        a = fmaf(c4.y, w1_s[kc * 4 + 1][c], a);
        a = fmaf(c4.z, w1_s[kc * 4 + 2][c], a);
        a = fmaf(c4.w, w1_s[kc * 4 + 3][c], a);
      }
      esum += fast_tanh(a) * w2_s[c];
    }
  }
  #pragma unroll
  for (int off = 32; off; off >>= 1) esum += __shfl_down(esum, off);
  if (l == 0) outg[bm] = esum + (float)n * b2g[0];
}

extern "C" void kernel_launch(void* const* d_in, const int* in_sizes, int n_in,
                              void* d_out, int out_size, void* d_ws, size_t ws_size,
                              hipStream_t stream) {
  (void)in_sizes; (void)n_in; (void)ws_size;
  const int*   Z   = (const int*)d_in[0];
  const float* D   = (const float*)d_in[1];
  const int*   sz  = (const int*)d_in[2];
  const float* emb = (const float*)d_in[3];
  const float* dfw = (const float*)d_in[4];
  const float* dfb = (const float*)d_in[5];
  const float* cfw = (const float*)d_in[6];
  const float* cfb = (const float*)d_in[7];
  const float* fcw = (const float*)d_in[8];
  const float* w1  = (const float*)d_in[9];
  const float* b1  = (const float*)d_in[10];
  const float* w2  = (const float*)d_in[11];
  const float* b2  = (const float*)d_in[12];
  float* out = (float*)d_out;
  const int B = out_size;  // 2048

  mdtnn_phA_mfma<<<dim3(B), dim3(256), 0, stream>>>(D, sz, dfw, dfb, (uint2*)d_ws);
  mdtnn_phB3<<<dim3((B + 3) / 4), dim3(256), 0, stream>>>(Z, sz, emb, cfw, cfb, fcw,
                                                          w1, b1, w2, b2,
                                                          (const unsigned*)d_ws, out, B);
}

// Round 11
// 119.203 us; speedup vs baseline: 1.8526x; 1.0337x over previous
//
#include <hip/hip_runtime.h>
#include <hip/hip_bf16.h>

typedef __attribute__((ext_vector_type(8))) short bh8;   // 8 x bf16 (4 VGPR) MFMA A/B frag
typedef __attribute__((ext_vector_type(4))) float f4;    // 4 x f32 MFMA C/D frag

#define MFMA_BF16 __builtin_amdgcn_mfma_f32_16x16x32_bf16

__device__ __forceinline__ float fast_tanh(float x) {
  float cl = fminf(fmaxf(x, -15.f), 15.f);
  float e = __builtin_amdgcn_exp2f(cl * 2.885390081777927f);  // exp(2x)
  return (e - 1.f) * __builtin_amdgcn_rcpf(e + 1.f);
}

__device__ __forceinline__ short bf16hi(float f, float* hf) {
  __hip_bfloat16 h = __float2bfloat16(f);
  *hf = __bfloat162float(h);
  short s;
  __builtin_memcpy(&s, &h, 2);
  return s;
}
__device__ __forceinline__ short bf16s(float f) {
  __hip_bfloat16 h = __float2bfloat16(f);
  short s;
  __builtin_memcpy(&s, &h, 2);
  return s;
}

__device__ __forceinline__ unsigned pack2_bf16(float a, float b) {
  unsigned ua = __float_as_uint(a);
  unsigned ub = __float_as_uint(b);
  ua = (ua + 0x7fffu + ((ua >> 16) & 1u)) >> 16;
  ub = (ub + 0x7fffu + ((ub >> 16) & 1u)) & 0xffff0000u;
  return ua | ub;
}

// d_hat layout: [b][i(30)][j(30)][h(32, bf16)] -> 64 B per (i,j) pair.

// ---------------------------------------------------------------------------
// Phase A (MFMA, unchanged since R7 — validated): d_hat = D@df_w+df_b -> global.
// ---------------------------------------------------------------------------
__global__ __launch_bounds__(256, 4) void mdtnn_phA_mfma(
    const float* __restrict__ Dg, const int* __restrict__ sizesg,
    const float* __restrict__ dfwg, const float* __restrict__ dfbg,
    uint2* __restrict__ dhg)
{
  const int b = blockIdx.x, tid = threadIdx.x;
  const int w = tid >> 6, l = tid & 63;
  const int lr = l & 15, lc = l >> 4;
  const int n = sizesg[b];
  const int nn = n * n;
  const unsigned inv = (65536u + (unsigned)n - 1) / (unsigned)n;  // exact p/n for p<1024

  bh8 Ah[2][2], Al[2][2];
  #pragma unroll
  for (int ht = 0; ht < 2; ++ht) {
    const int h = ht * 16 + lr;
    #pragma unroll
    for (int kc = 0; kc < 2; ++kc) {
      #pragma unroll
      for (int e = 0; e < 8; ++e) {
        const int g = kc * 32 + lc * 8 + e;
        float v = (g < 56 && h < 30) ? dfwg[g * 30 + h] : 0.f;
        float hf;
        Ah[ht][kc][e] = bf16hi(v, &hf);
        Al[ht][kc][e] = bf16s(v - hf);
      }
    }
  }
  float dfbv[2][4];
  #pragma unroll
  for (int ht = 0; ht < 2; ++ht)
    #pragma unroll
    for (int e = 0; e < 4; ++e) {
      const int h = ht * 16 + lc * 4 + e;
      dfbv[ht][e] = (h < 30) ? dfbg[h] : 0.f;
    }

  const float* Db = Dg + (size_t)b * (30 * 30 * 56);
  uint2* dhb = dhg + (size_t)b * (30 * 30 * 8);
  const f4 z4 = {0.f, 0.f, 0.f, 0.f};

  const int tiles = (nn + 15) >> 4;
  for (int t = w; t < tiles; t += 4) {
    const int p_raw = t * 16 + lr;
    const int p = min(p_raw, nn - 1);
    const int i = (int)(((unsigned)p * inv) >> 16);
    const int j = p - i * n;
    const int row = i * 30 + j;
    const float* Dp = Db + (size_t)row * 56;

    float4 q0 = *reinterpret_cast<const float4*>(Dp + lc * 8);
    float4 q1 = *reinterpret_cast<const float4*>(Dp + lc * 8 + 4);
    float4 q2 = {0.f, 0.f, 0.f, 0.f}, q3 = {0.f, 0.f, 0.f, 0.f};
    if (lc < 3) {
      q2 = *reinterpret_cast<const float4*>(Dp + 32 + lc * 8);
      q3 = *reinterpret_cast<const float4*>(Dp + 32 + lc * 8 + 4);
    }
    bh8 B0, B1;
    B0[0] = bf16s(q0.x); B0[1] = bf16s(q0.y); B0[2] = bf16s(q0.z); B0[3] = bf16s(q0.w);
    B0[4] = bf16s(q1.x); B0[5] = bf16s(q1.y); B0[6] = bf16s(q1.z); B0[7] = bf16s(q1.w);
    B1[0] = bf16s(q2.x); B1[1] = bf16s(q2.y); B1[2] = bf16s(q2.z); B1[3] = bf16s(q2.w);
    B1[4] = bf16s(q3.x); B1[5] = bf16s(q3.y); B1[6] = bf16s(q3.z); B1[7] = bf16s(q3.w);

    f4 a0 = z4, a1 = z4;
    a0 = MFMA_BF16(Al[0][0], B0, a0, 0, 0, 0);
    a0 = MFMA_BF16(Ah[0][0], B0, a0, 0, 0, 0);
    a0 = MFMA_BF16(Al[0][1], B1, a0, 0, 0, 0);
    a0 = MFMA_BF16(Ah[0][1], B1, a0, 0, 0, 0);
    a1 = MFMA_BF16(Al[1][0], B0, a1, 0, 0, 0);
    a1 = MFMA_BF16(Ah[1][0], B0, a1, 0, 0, 0);
    a1 = MFMA_BF16(Al[1][1], B1, a1, 0, 0, 0);
    a1 = MFMA_BF16(Ah[1][1], B1, a1, 0, 0, 0);

    if (p_raw < nn) {
      uint2 s0, s1;
      s0.x = pack2_bf16(a0[0] + dfbv[0][0], a0[1] + dfbv[0][1]);
      s0.y = pack2_bf16(a0[2] + dfbv[0][2], a0[3] + dfbv[0][3]);
      s1.x = pack2_bf16(a1[0] + dfbv[1][0], a1[1] + dfbv[1][1]);
      s1.y = pack2_bf16(a1[2] + dfbv[1][2], a1[3] + dfbv[1][3]);
      dhb[row * 8 + 0 * 4 + lc] = s0;
      dhb[row * 8 + 1 * 4 + lc] = s1;
    }
  }
}

// ---------------------------------------------------------------------------
// Phase B v4: ONE MOLECULE PER 128-THREAD BLOCK (2 waves). Both waves hold the
// full C in registers (duplicated, bitwise-identical updates). Per iteration:
//   each wave: spill C -> OWN LDS buf, read A-frags, 12 MFMAs -> X1 -> own buf
//   (redundant across waves; removes any pre-i-loop barrier);
//   i-loop over HALF the i-range (one-ahead dh prefetch, single-rounded W',
//   4 MFMAs + 16 tanh per i) -> inc registers;
//   write inc -> own buf, barrier, both waves read BOTH bufs and apply the
//   same-order C update, barrier.  2 barriers/iter, zero atomics.
// 2048 blocks -> 8 blocks/CU -> 12-16 waves/CU (vs R10's 8).
// ---------------------------------------------------------------------------
__global__ __launch_bounds__(128, 3) void mdtnn_phB4(
    const int* __restrict__ Zg, const int* __restrict__ sizesg,
    const float* __restrict__ embg, const float* __restrict__ cfwg,
    const float* __restrict__ cfbg, const float* __restrict__ fcwg,
    const float* __restrict__ w1g, const float* __restrict__ b1g,
    const float* __restrict__ w2g, const float* __restrict__ b2g,
    const unsigned* __restrict__ dhg, float* __restrict__ outg)
{
  const int tid = threadIdx.x;
  const int wid = tid >> 6, l = tid & 63;
  const int lr = l & 15, lc = l >> 4;
  const int bm = blockIdx.x;

  __shared__ __align__(16) float buf[2][32][36];   // per-wave bufs
  __shared__ __align__(16) float w1_s[32][16];
  __shared__ float b1_s[16], w2_s[16], wsum[2];

  for (int t = tid; t < 512; t += 128) {
    int k = t >> 4, c = t & 15;
    w1_s[k][c] = (k < 30 && c < 15) ? w1g[k * 15 + c] : 0.f;
  }
  if (tid < 16) {
    b1_s[tid] = (tid < 15) ? b1g[tid] : 0.f;
    w2_s[tid] = (tid < 15) ? w2g[tid] : 0.f;
  }

  const int n = sizesg[bm];
  float (*mybuf)[36] = buf[wid];

  // per-lane weights (contraction index kk = lc*8+e)
  float fcwF0[8], fcwF1[8];
  bh8 cfwB0h, cfwB0l, cfwB1h, cfwB1l;
  #pragma unroll
  for (int e = 0; e < 8; ++e) {
    const int kk = lc * 8 + e;
    const int c1 = lr + 16;
    fcwF0[e] = (kk < 30) ? fcwg[kk * 30 + lr] : 0.f;
    fcwF1[e] = (kk < 30 && c1 < 30) ? fcwg[kk * 30 + c1] : 0.f;
    float g0 = (kk < 30) ? cfwg[kk * 30 + lr] : 0.f;
    float g1 = (kk < 30 && c1 < 30) ? cfwg[kk * 30 + c1] : 0.f;
    float hf;
    cfwB0h[e] = bf16hi(g0, &hf);
    cfwB0l[e] = bf16s(g0 - hf);
    cfwB1h[e] = bf16hi(g1, &hf);
    cfwB1l[e] = bf16s(g1 - hf);
  }
  const float cfb0 = cfbg[lr];
  const float cfb1 = (lr + 16 < 30) ? cfbg[lr + 16] : 0.f;

  // C in registers, D-frag layout (duplicated in both waves)
  f4 C00, C01, C10, C11;
  #pragma unroll
  for (int e = 0; e < 4; ++e) {
    const int r0 = lc * 4 + e;
    const int r1 = 16 + lc * 4 + e;
    const int z0 = Zg[bm * 30 + r0];
    C00[e] = embg[z0 * 30 + lr];
    C01[e] = (lr + 16 < 30) ? embg[z0 * 30 + lr + 16] : 0.f;
    if (r1 < 30) {
      const int z1 = Zg[bm * 30 + r1];
      C10[e] = embg[z1 * 30 + lr];
      C11[e] = (lr + 16 < 30) ? embg[z1 * 30 + lr + 16] : 0.f;
    } else {
      C10[e] = 0.f;
      C11[e] = 0.f;
    }
  }

  const unsigned* dhb = dhg + (size_t)bm * 14400;   // dwords
  const int n0 = (n + 1) >> 1;
  const int ibeg = wid ? n0 : 0;
  const int iend = wid ? n : n0;
  const f4 z4 = {0.f, 0.f, 0.f, 0.f};

  __syncthreads();   // staging done; bufs free

  for (int it = 0; it < 3; ++it) {
    // prefetch first dh of this wave's range (overlaps X1 compute)
    uint4 a0c = {0, 0, 0, 0}, a1c = {0, 0, 0, 0};
    if (ibeg < iend) {
      const unsigned* p = dhb + (size_t)ibeg * 480;
      if (lr < n)      a0c = *reinterpret_cast<const uint4*>(p + lr * 16 + lc * 4);
      if (lr + 16 < n) a1c = *reinterpret_cast<const uint4*>(p + lr * 16 + 256 + lc * 4);
    }

    // ---- X1 (redundant per wave): spill C, read A-frags, 12 MFMAs, write X1 ----
    #pragma unroll
    for (int e = 0; e < 4; ++e) {
      mybuf[lc * 4 + e][lr]           = C00[e];
      mybuf[lc * 4 + e][lr + 16]      = C01[e];
      mybuf[16 + lc * 4 + e][lr]      = C10[e];
      mybuf[16 + lc * 4 + e][lr + 16] = C11[e];
    }
    float cv0[8], cv1[8];
    *reinterpret_cast<float4*>(&cv0[0]) = *reinterpret_cast<const float4*>(&mybuf[lr][lc * 8]);
    *reinterpret_cast<float4*>(&cv0[4]) = *reinterpret_cast<const float4*>(&mybuf[lr][lc * 8 + 4]);
    *reinterpret_cast<float4*>(&cv1[0]) = *reinterpret_cast<const float4*>(&mybuf[16 + lr][lc * 8]);
    *reinterpret_cast<float4*>(&cv1[4]) = *reinterpret_cast<const float4*>(&mybuf[16 + lr][lc * 8 + 4]);
    bh8 Ch0, Cl0, Ch1, Cl1;
    #pragma unroll
    for (int e = 0; e < 8; ++e) {
      float hf;
      Ch0[e] = bf16hi(cv0[e], &hf);
      Cl0[e] = bf16s(cv0[e] - hf);
      Ch1[e] = bf16hi(cv1[e], &hf);
      Cl1[e] = bf16s(cv1[e] - hf);
    }
    f4 d00 = MFMA_BF16(Ch0, cfwB0l, z4, 0, 0, 0);
    d00 = MFMA_BF16(Cl0, cfwB0h, d00, 0, 0, 0);
    d00 = MFMA_BF16(Ch0, cfwB0h, d00, 0, 0, 0);
    f4 d01 = MFMA_BF16(Ch0, cfwB1l, z4, 0, 0, 0);
    d01 = MFMA_BF16(Cl0, cfwB1h, d01, 0, 0, 0);
    d01 = MFMA_BF16(Ch0, cfwB1h, d01, 0, 0, 0);
    f4 d10 = MFMA_BF16(Ch1, cfwB0l, z4, 0, 0, 0);
    d10 = MFMA_BF16(Cl1, cfwB0h, d10, 0, 0, 0);
    d10 = MFMA_BF16(Ch1, cfwB0h, d10, 0, 0, 0);
    f4 d11 = MFMA_BF16(Ch1, cfwB1l, z4, 0, 0, 0);
    d11 = MFMA_BF16(Cl1, cfwB1h, d11, 0, 0, 0);
    d11 = MFMA_BF16(Ch1, cfwB1h, d11, 0, 0, 0);
    #pragma unroll
    for (int e = 0; e < 4; ++e) {
      mybuf[lc * 4 + e][lr]           = d00[e] + cfb0;
      mybuf[lc * 4 + e][lr + 16]      = d01[e] + cfb1;
      mybuf[16 + lc * 4 + e][lr]      = d10[e] + cfb0;
      mybuf[16 + lc * 4 + e][lr + 16] = d11[e] + cfb1;
    }

    // ---- i-loop over this wave's half (wave-private) ----
    f4 i00 = z4, i01 = z4, i10 = z4, i11 = z4;
    for (int i = ibeg; i < iend; ++i) {
      uint4 a0n = {0, 0, 0, 0}, a1n = {0, 0, 0, 0};
      if (i + 1 < iend) {
        const unsigned* p = dhb + (size_t)(i + 1) * 480;
        if (lr < n)      a0n = *reinterpret_cast<const uint4*>(p + lr * 16 + lc * 4);
        if (lr + 16 < n) a1n = *reinterpret_cast<const uint4*>(p + lr * 16 + 256 + lc * 4);
      }
      float4 xA = *reinterpret_cast<const float4*>(&mybuf[i][lc * 8]);
      float4 xB = *reinterpret_cast<const float4*>(&mybuf[i][lc * 8 + 4]);
      float xv[8] = {xA.x, xA.y, xA.z, xA.w, xB.x, xB.y, xB.z, xB.w};
      bh8 W0, W1;
      #pragma unroll
      for (int e = 0; e < 8; ++e) {
        W0[e] = bf16s(xv[e] * fcwF0[e]);
        W1[e] = bf16s(xv[e] * fcwF1[e]);
      }
      const bh8 A0 = *reinterpret_cast<const bh8*>(&a0c);
      const bh8 A1 = *reinterpret_cast<const bh8*>(&a1c);
      f4 g;
      g = MFMA_BF16(A0, W0, z4, 0, 0, 0);
      #pragma unroll
      for (int e = 0; e < 4; ++e) i00[e] += fast_tanh(g[e]);
      g = MFMA_BF16(A0, W1, z4, 0, 0, 0);
      #pragma unroll
      for (int e = 0; e < 4; ++e) i01[e] += fast_tanh(g[e]);
      g = MFMA_BF16(A1, W0, z4, 0, 0, 0);
      #pragma unroll
      for (int e = 0; e < 4; ++e) i10[e] += fast_tanh(g[e]);
      g = MFMA_BF16(A1, W1, z4, 0, 0, 0);
      #pragma unroll
      for (int e = 0; e < 4; ++e) i11[e] += fast_tanh(g[e]);
      a0c = a0n;
      a1c = a1n;
    }

    // ---- inc exchange: write own, barrier, read both in fixed order ----
    #pragma unroll
    for (int e = 0; e < 4; ++e) {
      mybuf[lc * 4 + e][lr]           = i00[e];
      mybuf[lc * 4 + e][lr + 16]      = i01[e];
      mybuf[16 + lc * 4 + e][lr]      = i10[e];
      mybuf[16 + lc * 4 + e][lr + 16] = i11[e];
    }
    __syncthreads();
    #pragma unroll
    for (int e = 0; e < 4; ++e) {
      C00[e] += buf[0][lc * 4 + e][lr];
      C00[e] += buf[1][lc * 4 + e][lr];
      C01[e] += buf[0][lc * 4 + e][lr + 16];
      C01[e] += buf[1][lc * 4 + e][lr + 16];
      C10[e] += buf[0][16 + lc * 4 + e][lr];
      C10[e] += buf[1][16 + lc * 4 + e][lr];
      C11[e] += buf[0][16 + lc * 4 + e][lr + 16];
      C11[e] += buf[1][16 + lc * 4 + e][lr + 16];
    }
    __syncthreads();   // protect bufs before next iteration's X1 write
  }

  // ---- head: each wave spills its (identical) C to own buf; split rows ----
  #pragma unroll
  for (int e = 0; e < 4; ++e) {
    mybuf[lc * 4 + e][lr]           = C00[e];
    mybuf[lc * 4 + e][lr + 16]      = C01[e];
    mybuf[16 + lc * 4 + e][lr]      = C10[e];
    mybuf[16 + lc * 4 + e][lr + 16] = C11[e];
  }
  float esum = 0.f;
  for (int t = l + wid * 64; t < n * 16; t += 128) {
    int j = t >> 4, c = t & 15;
    if (c < 15) {
      float a = b1_s[c];
      #pragma unroll
      for (int kc = 0; kc < 8; ++kc) {
        float4 c4 = *reinterpret_cast<const float4*>(&mybuf[j][kc * 4]);
        a = fmaf(c4.x, w1_s[kc * 4 + 0][c], a);
        a = fmaf(c4.y, w1_s[kc * 4 + 1][c], a);
        a = fmaf(c4.z, w1_s[kc * 4 + 2][c], a);
        a = fmaf(c4.w, w1_s[kc * 4 + 3][c], a);
      }
      esum += fast_tanh(a) * w2_s[c];
    }
  }
  #pragma unroll
  for (int off = 32; off; off >>= 1) esum += __shfl_down(esum, off);
  if (l == 0) wsum[wid] = esum;
  __syncthreads();
  if (tid == 0) outg[bm] = wsum[0] + wsum[1] + (float)n * b2g[0];
}

extern "C" void kernel_launch(void* const* d_in, const int* in_sizes, int n_in,
                              void* d_out, int out_size, void* d_ws, size_t ws_size,
                              hipStream_t stream) {
  (void)in_sizes; (void)n_in; (void)ws_size;
  const int*   Z   = (const int*)d_in[0];
  const float* D   = (const float*)d_in[1];
  const int*   sz  = (const int*)d_in[2];
  const float* emb = (const float*)d_in[3];
  const float* dfw = (const float*)d_in[4];
  const float* dfb = (const float*)d_in[5];
  const float* cfw = (const float*)d_in[6];
  const float* cfb = (const float*)d_in[7];
  const float* fcw = (const float*)d_in[8];
  const float* w1  = (const float*)d_in[9];
  const float* b1  = (const float*)d_in[10];
  const float* w2  = (const float*)d_in[11];
  const float* b2  = (const float*)d_in[12];
  float* out = (float*)d_out;
  const int B = out_size;  // 2048

  mdtnn_phA_mfma<<<dim3(B), dim3(256), 0, stream>>>(D, sz, dfw, dfb, (uint2*)d_ws);
  mdtnn_phB4<<<dim3(B), dim3(128), 0, stream>>>(Z, sz, emb, cfw, cfb, fcw,
                                                w1, b1, w2, b2,
                                                (const unsigned*)d_ws, out);
}

// Round 12
// 108.462 us; speedup vs baseline: 2.0360x; 1.0990x over previous
//
#include <hip/hip_runtime.h>
#include <hip/hip_bf16.h>

typedef __attribute__((ext_vector_type(8))) short bh8;   // 8 x bf16 (4 VGPR) MFMA A/B frag
typedef __attribute__((ext_vector_type(4))) float f4;    // 4 x f32 MFMA C/D frag

#define MFMA_BF16 __builtin_amdgcn_mfma_f32_16x16x32_bf16

// packed f32x2 -> bf16x2 (RNE), dst.lo = a, dst.hi = b  [T12 recipe]
__device__ __forceinline__ unsigned cvtpk(float a, float b) {
  unsigned r;
  asm("v_cvt_pk_bf16_f32 %0, %1, %2" : "=v"(r) : "v"(a), "v"(b));
  return r;
}
__device__ __forceinline__ bh8 mk_bh8(unsigned a, unsigned b, unsigned c, unsigned d) {
  uint4 u;
  u.x = a; u.y = b; u.z = c; u.w = d;
  return __builtin_bit_cast(bh8, u);
}

// tanh(x) = 1 - 2/(e^{2x}+1); clamp-free (exp2->inf => 1, ->0 => -1). 4 insts.
__device__ __forceinline__ float fast_tanh(float x) {
  float e = __builtin_amdgcn_exp2f(x * 2.885390081777927f);
  return fmaf(-2.f, __builtin_amdgcn_rcpf(e + 1.f), 1.f);
}

// scalar RNE casts (cold paths only)
__device__ __forceinline__ short bf16hi(float f, float* hf) {
  __hip_bfloat16 h = __float2bfloat16(f);
  *hf = __bfloat162float(h);
  short s;
  __builtin_memcpy(&s, &h, 2);
  return s;
}
__device__ __forceinline__ short bf16s(float f) {
  __hip_bfloat16 h = __float2bfloat16(f);
  short s;
  __builtin_memcpy(&s, &h, 2);
  return s;
}

// d_hat layout: [b][i(30)][j(30)][h(32, bf16)] -> 64 B per (i,j) pair.

// ---------------------------------------------------------------------------
// Phase A (MFMA): d_hat = D@df_w+df_b -> global bf16. Hot converts via cvt_pk.
// ---------------------------------------------------------------------------
__global__ __launch_bounds__(256, 4) void mdtnn_phA_mfma(
    const float* __restrict__ Dg, const int* __restrict__ sizesg,
    const float* __restrict__ dfwg, const float* __restrict__ dfbg,
    uint2* __restrict__ dhg)
{
  const int b = blockIdx.x, tid = threadIdx.x;
  const int w = tid >> 6, l = tid & 63;
  const int lr = l & 15, lc = l >> 4;
  const int n = sizesg[b];
  const int nn = n * n;
  const unsigned inv = (65536u + (unsigned)n - 1) / (unsigned)n;  // exact p/n for p<1024

  bh8 Ah[2][2], Al[2][2];
  #pragma unroll
  for (int ht = 0; ht < 2; ++ht) {
    const int h = ht * 16 + lr;
    #pragma unroll
    for (int kc = 0; kc < 2; ++kc) {
      #pragma unroll
      for (int e = 0; e < 8; ++e) {
        const int g = kc * 32 + lc * 8 + e;
        float v = (g < 56 && h < 30) ? dfwg[g * 30 + h] : 0.f;
        float hf;
        Ah[ht][kc][e] = bf16hi(v, &hf);
        Al[ht][kc][e] = bf16s(v - hf);
      }
    }
  }
  float dfbv[2][4];
  #pragma unroll
  for (int ht = 0; ht < 2; ++ht)
    #pragma unroll
    for (int e = 0; e < 4; ++e) {
      const int h = ht * 16 + lc * 4 + e;
      dfbv[ht][e] = (h < 30) ? dfbg[h] : 0.f;
    }

  const float* Db = Dg + (size_t)b * (30 * 30 * 56);
  uint2* dhb = dhg + (size_t)b * (30 * 30 * 8);
  const f4 z4 = {0.f, 0.f, 0.f, 0.f};

  const int tiles = (nn + 15) >> 4;
  for (int t = w; t < tiles; t += 4) {
    const int p_raw = t * 16 + lr;
    const int p = min(p_raw, nn - 1);
    const int i = (int)(((unsigned)p * inv) >> 16);
    const int j = p - i * n;
    const int row = i * 30 + j;
    const float* Dp = Db + (size_t)row * 56;

    float4 q0 = *reinterpret_cast<const float4*>(Dp + lc * 8);
    float4 q1 = *reinterpret_cast<const float4*>(Dp + lc * 8 + 4);
    float4 q2 = {0.f, 0.f, 0.f, 0.f}, q3 = {0.f, 0.f, 0.f, 0.f};
    if (lc < 3) {
      q2 = *reinterpret_cast<const float4*>(Dp + 32 + lc * 8);
      q3 = *reinterpret_cast<const float4*>(Dp + 32 + lc * 8 + 4);
    }
    bh8 B0 = mk_bh8(cvtpk(q0.x, q0.y), cvtpk(q0.z, q0.w),
                    cvtpk(q1.x, q1.y), cvtpk(q1.z, q1.w));
    bh8 B1 = mk_bh8(cvtpk(q2.x, q2.y), cvtpk(q2.z, q2.w),
                    cvtpk(q3.x, q3.y), cvtpk(q3.z, q3.w));

    f4 a0 = z4, a1 = z4;
    a0 = MFMA_BF16(Al[0][0], B0, a0, 0, 0, 0);
    a0 = MFMA_BF16(Ah[0][0], B0, a0, 0, 0, 0);
    a0 = MFMA_BF16(Al[0][1], B1, a0, 0, 0, 0);
    a0 = MFMA_BF16(Ah[0][1], B1, a0, 0, 0, 0);
    a1 = MFMA_BF16(Al[1][0], B0, a1, 0, 0, 0);
    a1 = MFMA_BF16(Ah[1][0], B0, a1, 0, 0, 0);
    a1 = MFMA_BF16(Al[1][1], B1, a1, 0, 0, 0);
    a1 = MFMA_BF16(Ah[1][1], B1, a1, 0, 0, 0);

    if (p_raw < nn) {
      uint2 s0, s1;
      s0.x = cvtpk(a0[0] + dfbv[0][0], a0[1] + dfbv[0][1]);
      s0.y = cvtpk(a0[2] + dfbv[0][2], a0[3] + dfbv[0][3]);
      s1.x = cvtpk(a1[0] + dfbv[1][0], a1[1] + dfbv[1][1]);
      s1.y = cvtpk(a1[2] + dfbv[1][2], a1[3] + dfbv[1][3]);
      dhb[row * 8 + 0 * 4 + lc] = s0;
      dhb[row * 8 + 1 * 4 + lc] = s1;
    }
  }
}

// ---------------------------------------------------------------------------
// Phase B v5 (= R11 structure, VALU-slimmed): one molecule per 128-thr block,
// 2 waves, duplicated C in regs, wave-private X1 bufs, i-range halved,
// 2 barriers/iter, zero atomics. W' and C-splits via packed cvt.
// ---------------------------------------------------------------------------
__global__ __launch_bounds__(128, 3) void mdtnn_phB5(
    const int* __restrict__ Zg, const int* __restrict__ sizesg,
    const float* __restrict__ embg, const float* __restrict__ cfwg,
    const float* __restrict__ cfbg, const float* __restrict__ fcwg,
    const float* __restrict__ w1g, const float* __restrict__ b1g,
    const float* __restrict__ w2g, const float* __restrict__ b2g,
    const unsigned* __restrict__ dhg, float* __restrict__ outg)
{
  const int tid = threadIdx.x;
  const int wid = tid >> 6, l = tid & 63;
  const int lr = l & 15, lc = l >> 4;
  const int bm = blockIdx.x;

  __shared__ __align__(16) float buf[2][32][36];   // per-wave bufs
  __shared__ __align__(16) float w1_s[32][16];
  __shared__ float b1_s[16], w2_s[16], wsum[2];

  for (int t = tid; t < 512; t += 128) {
    int k = t >> 4, c = t & 15;
    w1_s[k][c] = (k < 30 && c < 15) ? w1g[k * 15 + c] : 0.f;
  }
  if (tid < 16) {
    b1_s[tid] = (tid < 15) ? b1g[tid] : 0.f;
    w2_s[tid] = (tid < 15) ? w2g[tid] : 0.f;
  }

  const int n = sizesg[bm];
  float (*mybuf)[36] = buf[wid];

  // per-lane weights (contraction index kk = lc*8+e)
  float fcwF0[8], fcwF1[8];
  bh8 cfwB0h, cfwB0l, cfwB1h, cfwB1l;
  #pragma unroll
  for (int e = 0; e < 8; ++e) {
    const int kk = lc * 8 + e;
    const int c1 = lr + 16;
    fcwF0[e] = (kk < 30) ? fcwg[kk * 30 + lr] : 0.f;
    fcwF1[e] = (kk < 30 && c1 < 30) ? fcwg[kk * 30 + c1] : 0.f;
    float g0 = (kk < 30) ? cfwg[kk * 30 + lr] : 0.f;
    float g1 = (kk < 30 && c1 < 30) ? cfwg[kk * 30 + c1] : 0.f;
    float hf;
    cfwB0h[e] = bf16hi(g0, &hf);
    cfwB0l[e] = bf16s(g0 - hf);
    cfwB1h[e] = bf16hi(g1, &hf);
    cfwB1l[e] = bf16s(g1 - hf);
  }
  const float cfb0 = cfbg[lr];
  const float cfb1 = (lr + 16 < 30) ? cfbg[lr + 16] : 0.f;

  // C in registers, D-frag layout (duplicated in both waves)
  f4 C00, C01, C10, C11;
  #pragma unroll
  for (int e = 0; e < 4; ++e) {
    const int r0 = lc * 4 + e;
    const int r1 = 16 + lc * 4 + e;
    const int z0 = Zg[bm * 30 + r0];
    C00[e] = embg[z0 * 30 + lr];
    C01[e] = (lr + 16 < 30) ? embg[z0 * 30 + lr + 16] : 0.f;
    if (r1 < 30) {
      const int z1 = Zg[bm * 30 + r1];
      C10[e] = embg[z1 * 30 + lr];
      C11[e] = (lr + 16 < 30) ? embg[z1 * 30 + lr + 16] : 0.f;
    } else {
      C10[e] = 0.f;
      C11[e] = 0.f;
    }
  }

  const unsigned* dhb = dhg + (size_t)bm * 14400;   // dwords
  const int n0 = (n + 1) >> 1;
  const int ibeg = wid ? n0 : 0;
  const int iend = wid ? n : n0;
  const f4 z4 = {0.f, 0.f, 0.f, 0.f};

  __syncthreads();   // staging done; bufs free

  for (int it = 0; it < 3; ++it) {
    // prefetch first dh of this wave's range (overlaps X1 compute)
    uint4 a0c = {0, 0, 0, 0}, a1c = {0, 0, 0, 0};
    if (ibeg < iend) {
      const unsigned* p = dhb + (size_t)ibeg * 480;
      if (lr < n)      a0c = *reinterpret_cast<const uint4*>(p + lr * 16 + lc * 4);
      if (lr + 16 < n) a1c = *reinterpret_cast<const uint4*>(p + lr * 16 + 256 + lc * 4);
    }

    // ---- X1 (redundant per wave): spill C, read A-frags, 12 MFMAs, write X1 ----
    #pragma unroll
    for (int e = 0; e < 4; ++e) {
      mybuf[lc * 4 + e][lr]           = C00[e];
      mybuf[lc * 4 + e][lr + 16]      = C01[e];
      mybuf[16 + lc * 4 + e][lr]      = C10[e];
      mybuf[16 + lc * 4 + e][lr + 16] = C11[e];
    }
    float cv0[8], cv1[8];
    *reinterpret_cast<float4*>(&cv0[0]) = *reinterpret_cast<const float4*>(&mybuf[lr][lc * 8]);
    *reinterpret_cast<float4*>(&cv0[4]) = *reinterpret_cast<const float4*>(&mybuf[lr][lc * 8 + 4]);
    *reinterpret_cast<float4*>(&cv1[0]) = *reinterpret_cast<const float4*>(&mybuf[16 + lr][lc * 8]);
    *reinterpret_cast<float4*>(&cv1[4]) = *reinterpret_cast<const float4*>(&mybuf[16 + lr][lc * 8 + 4]);

    // packed hi/lo split: hi = RNE(cv) (pk), lo = RNE(cv - f32(hi)) (pk)
    unsigned h_[4], lo_[4];
    #pragma unroll
    for (int q = 0; q < 4; ++q) {
      unsigned hq = cvtpk(cv0[2 * q], cv0[2 * q + 1]);
      float f0 = __uint_as_float(hq << 16);
      float f1 = __uint_as_float(hq & 0xffff0000u);
      h_[q] = hq;
      lo_[q] = cvtpk(cv0[2 * q] - f0, cv0[2 * q + 1] - f1);
    }
    bh8 Ch0 = mk_bh8(h_[0], h_[1], h_[2], h_[3]);
    bh8 Cl0 = mk_bh8(lo_[0], lo_[1], lo_[2], lo_[3]);
    #pragma unroll
    for (int q = 0; q < 4; ++q) {
      unsigned hq = cvtpk(cv1[2 * q], cv1[2 * q + 1]);
      float f0 = __uint_as_float(hq << 16);
      float f1 = __uint_as_float(hq & 0xffff0000u);
      h_[q] = hq;
      lo_[q] = cvtpk(cv1[2 * q] - f0, cv1[2 * q + 1] - f1);
    }
    bh8 Ch1 = mk_bh8(h_[0], h_[1], h_[2], h_[3]);
    bh8 Cl1 = mk_bh8(lo_[0], lo_[1], lo_[2], lo_[3]);

    f4 d00 = MFMA_BF16(Ch0, cfwB0l, z4, 0, 0, 0);
    d00 = MFMA_BF16(Cl0, cfwB0h, d00, 0, 0, 0);
    d00 = MFMA_BF16(Ch0, cfwB0h, d00, 0, 0, 0);
    f4 d01 = MFMA_BF16(Ch0, cfwB1l, z4, 0, 0, 0);
    d01 = MFMA_BF16(Cl0, cfwB1h, d01, 0, 0, 0);
    d01 = MFMA_BF16(Ch0, cfwB1h, d01, 0, 0, 0);
    f4 d10 = MFMA_BF16(Ch1, cfwB0l, z4, 0, 0, 0);
    d10 = MFMA_BF16(Cl1, cfwB0h, d10, 0, 0, 0);
    d10 = MFMA_BF16(Ch1, cfwB0h, d10, 0, 0, 0);
    f4 d11 = MFMA_BF16(Ch1, cfwB1l, z4, 0, 0, 0);
    d11 = MFMA_BF16(Cl1, cfwB1h, d11, 0, 0, 0);
    d11 = MFMA_BF16(Ch1, cfwB1h, d11, 0, 0, 0);
    #pragma unroll
    for (int e = 0; e < 4; ++e) {
      mybuf[lc * 4 + e][lr]           = d00[e] + cfb0;
      mybuf[lc * 4 + e][lr + 16]      = d01[e] + cfb1;
      mybuf[16 + lc * 4 + e][lr]      = d10[e] + cfb0;
      mybuf[16 + lc * 4 + e][lr + 16] = d11[e] + cfb1;
    }

    // ---- i-loop over this wave's half (wave-private) ----
    f4 i00 = z4, i01 = z4, i10 = z4, i11 = z4;
    for (int i = ibeg; i < iend; ++i) {
      uint4 a0n = {0, 0, 0, 0}, a1n = {0, 0, 0, 0};
      if (i + 1 < iend) {
        const unsigned* p = dhb + (size_t)(i + 1) * 480;
        if (lr < n)      a0n = *reinterpret_cast<const uint4*>(p + lr * 16 + lc * 4);
        if (lr + 16 < n) a1n = *reinterpret_cast<const uint4*>(p + lr * 16 + 256 + lc * 4);
      }
      float4 xA = *reinterpret_cast<const float4*>(&mybuf[i][lc * 8]);
      float4 xB = *reinterpret_cast<const float4*>(&mybuf[i][lc * 8 + 4]);
      float xv[8] = {xA.x, xA.y, xA.z, xA.w, xB.x, xB.y, xB.z, xB.w};
      bh8 W0 = mk_bh8(cvtpk(xv[0] * fcwF0[0], xv[1] * fcwF0[1]),
                      cvtpk(xv[2] * fcwF0[2], xv[3] * fcwF0[3]),
                      cvtpk(xv[4] * fcwF0[4], xv[5] * fcwF0[5]),
                      cvtpk(xv[6] * fcwF0[6], xv[7] * fcwF0[7]));
      bh8 W1 = mk_bh8(cvtpk(xv[0] * fcwF1[0], xv[1] * fcwF1[1]),
                      cvtpk(xv[2] * fcwF1[2], xv[3] * fcwF1[3]),
                      cvtpk(xv[4] * fcwF1[4], xv[5] * fcwF1[5]),
                      cvtpk(xv[6] * fcwF1[6], xv[7] * fcwF1[7]));
      const bh8 A0 = *reinterpret_cast<const bh8*>(&a0c);
      const bh8 A1 = *reinterpret_cast<const bh8*>(&a1c);
      f4 g;
      g = MFMA_BF16(A0, W0, z4, 0, 0, 0);
      #pragma unroll
      for (int e = 0; e < 4; ++e) i00[e] += fast_tanh(g[e]);
      g = MFMA_BF16(A0, W1, z4, 0, 0, 0);
      #pragma unroll
      for (int e = 0; e < 4; ++e) i01[e] += fast_tanh(g[e]);
      g = MFMA_BF16(A1, W0, z4, 0, 0, 0);
      #pragma unroll
      for (int e = 0; e < 4; ++e) i10[e] += fast_tanh(g[e]);
      g = MFMA_BF16(A1, W1, z4, 0, 0, 0);
      #pragma unroll
      for (int e = 0; e < 4; ++e) i11[e] += fast_tanh(g[e]);
      a0c = a0n;
      a1c = a1n;
    }

    // ---- inc exchange: write own, barrier, read both in fixed order ----
    #pragma unroll
    for (int e = 0; e < 4; ++e) {
      mybuf[lc * 4 + e][lr]           = i00[e];
      mybuf[lc * 4 + e][lr + 16]      = i01[e];
      mybuf[16 + lc * 4 + e][lr]      = i10[e];
      mybuf[16 + lc * 4 + e][lr + 16] = i11[e];
    }
    __syncthreads();
    #pragma unroll
    for (int e = 0; e < 4; ++e) {
      C00[e] += buf[0][lc * 4 + e][lr];
      C00[e] += buf[1][lc * 4 + e][lr];
      C01[e] += buf[0][lc * 4 + e][lr + 16];
      C01[e] += buf[1][lc * 4 + e][lr + 16];
      C10[e] += buf[0][16 + lc * 4 + e][lr];
      C10[e] += buf[1][16 + lc * 4 + e][lr];
      C11[e] += buf[0][16 + lc * 4 + e][lr + 16];
      C11[e] += buf[1][16 + lc * 4 + e][lr + 16];
    }
    __syncthreads();   // protect bufs before next iteration's X1 write
  }

  // ---- head: each wave spills its (identical) C to own buf; split rows ----
  #pragma unroll
  for (int e = 0; e < 4; ++e) {
    mybuf[lc * 4 + e][lr]           = C00[e];
    mybuf[lc * 4 + e][lr + 16]      = C01[e];
    mybuf[16 + lc * 4 + e][lr]      = C10[e];
    mybuf[16 + lc * 4 + e][lr + 16] = C11[e];
  }
  float esum = 0.f;
  for (int t = l + wid * 64; t < n * 16; t += 128) {
    int j = t >> 4, c = t & 15;
    if (c < 15) {
      float a = b1_s[c];
      #pragma unroll
      for (int kc = 0; kc < 8; ++kc) {
        float4 c4 = *reinterpret_cast<const float4*>(&mybuf[j][kc * 4]);
        a = fmaf(c4.x, w1_s[kc * 4 + 0][c], a);
        a = fmaf(c4.y, w1_s[kc * 4 + 1][c], a);
        a = fmaf(c4.z, w1_s[kc * 4 + 2][c], a);
        a = fmaf(c4.w, w1_s[kc * 4 + 3][c], a);
      }
      esum += fast_tanh(a) * w2_s[c];
    }
  }
  #pragma unroll
  for (int off = 32; off; off >>= 1) esum += __shfl_down(esum, off);
  if (l == 0) wsum[wid] = esum;
  __syncthreads();
  if (tid == 0) outg[bm] = wsum[0] + wsum[1] + (float)n * b2g[0];
}

extern "C" void kernel_launch(void* const* d_in, const int* in_sizes, int n_in,
                              void* d_out, int out_size, void* d_ws, size_t ws_size,
                              hipStream_t stream) {
  (void)in_sizes; (void)n_in; (void)ws_size;
  const int*   Z   = (const int*)d_in[0];
  const float* D   = (const float*)d_in[1];
  const int*   sz  = (const int*)d_in[2];
  const float* emb = (const float*)d_in[3];
  const float* dfw = (const float*)d_in[4];
  const float* dfb = (const float*)d_in[5];
  const float* cfw = (const float*)d_in[6];
  const float* cfb = (const float*)d_in[7];
  const float* fcw = (const float*)d_in[8];
  const float* w1  = (const float*)d_in[9];
  const float* b1  = (const float*)d_in[10];
  const float* w2  = (const float*)d_in[11];
  const float* b2  = (const float*)d_in[12];
  float* out = (float*)d_out;
  const int B = out_size;  // 2048

  mdtnn_phA_mfma<<<dim3(B), dim3(256), 0, stream>>>(D, sz, dfw, dfb, (uint2*)d_ws);
  mdtnn_phB5<<<dim3(B), dim3(128), 0, stream>>>(Z, sz, emb, cfw, cfb, fcw,
                                                w1, b1, w2, b2,
                                                (const unsigned*)d_ws, out);
}